// Round 3
// baseline (515.441 us; speedup 1.0000x reference)
//
#include <hip/hip_runtime.h>

// Batched dynamic-filter cross-correlation:
// x: [128, 384, 384, 1] f32, k: [128, 8, 8, 1] f32
// out[b,i,j] = sum_{p,q} x[b,i+p,j+q] * k[b,p,q], out: [128, 377, 377, 1]

#define BATCH 128
#define Hh 384
#define Ww 384
#define KH 8
#define KW 8
#define OH 377
#define OW 377

#define TI 64                  // output rows per block
#define TJ 128                 // output cols per block
#define XRW (TI + KH - 1)      // 71 staged rows
#define XC4 34                 // float4 per staged row (136 floats >= 128+7)
#define XSTRIDE 136            // LDS row stride in floats (multiple of 4 -> b128 aligned)

// Lane mapping (store-coalescing-first):
//   c32 = lane & 31  -> float4 col group: cols 4*c32 .. 4*c32+3 (lanes 0-31 span 128 contiguous cols)
//   l5  = lane >> 5  -> row half: +0 or +8
//   wave w owns rows 16w .. 16w+15
// One float4 store instr = lanes 0-31 contiguous 512B (row R) + lanes 32-63 contiguous 512B (row R+8).

__global__ __launch_bounds__(256, 4) void corr_kernel(
    const float* __restrict__ x,
    const float* __restrict__ k,
    float* __restrict__ out) {

    __shared__ float xs[XRW * XSTRIDE];   // 38,624 B

    const int tj = blockIdx.x;           // 0..2
    const int ti = blockIdx.y;           // 0..5
    const int b  = blockIdx.z;           // 0..127

    const int bi  = ti * TI;
    const int bj  = tj * TJ;
    const int tid = (int)threadIdx.x;

    // ---- stage x tile: rows bi..bi+70, cols bj..bj+135 (zero-fill OOB) ----
    const float* xb = x + (size_t)b * (Hh * Ww);
    for (int idx = tid; idx < XRW * XC4; idx += 256) {
        const int r    = idx / XC4;
        const int c4   = idx - r * XC4;
        const int grow = bi + r;
        const int gcol = bj + c4 * 4;
        float4 v = make_float4(0.f, 0.f, 0.f, 0.f);
        if (grow < Hh) {
            const float* rp = xb + (size_t)grow * Ww + gcol;
            if (gcol + 3 < Ww) {
                v = *(const float4*)rp;
            } else {
                if (gcol + 0 < Ww) v.x = rp[0];
                if (gcol + 1 < Ww) v.y = rp[1];
                if (gcol + 2 < Ww) v.z = rp[2];
                if (gcol + 3 < Ww) v.w = rp[3];
            }
        }
        *(float4*)(&xs[r * XSTRIDE + c4 * 4]) = v;
    }

    // ---- k through a uniform pointer with static indices -> SGPRs ----
    const float* kg = k + (size_t)b * (KH * KW);
    float ka[64];
#pragma unroll
    for (int i = 0; i < 64; ++i) ka[i] = kg[i];

    __syncthreads();

    // ---- compute: 8 rows x 4 cols per thread ----
    const int w   = tid >> 6;            // wave 0..3
    const int l   = tid & 63;
    const int c32 = l & 31;
    const int l5  = l >> 5;
    const int tr  = w * 16 + l5 * 8;     // thread's first output row (local, 0..56)
    const int tc  = c32 * 4;             // thread's first output col (local, 0..124)

    float acc[8][4];
#pragma unroll
    for (int r = 0; r < 8; ++r)
#pragma unroll
        for (int cc = 0; cc < 4; ++cc) acc[r][cc] = 0.f;

#pragma unroll
    for (int s = 0; s < 15; ++s) {       // x rows tr+0 .. tr+14
        const float* rp = &xs[(tr + s) * XSTRIDE + tc];
        float4 a0 = *(const float4*)(rp + 0);
        float4 a1 = *(const float4*)(rp + 4);
        float4 a2 = *(const float4*)(rp + 8);
        float wv[12] = {a0.x, a0.y, a0.z, a0.w,
                        a1.x, a1.y, a1.z, a1.w,
                        a2.x, a2.y, a2.z, a2.w};
#pragma unroll
        for (int p = 0; p < 8; ++p) {
            if (s - p < 0 || s - p > 7) continue;   // compile-time predicate
            const int r = s - p;
#pragma unroll
            for (int cc = 0; cc < 4; ++cc)
#pragma unroll
                for (int q = 0; q < 8; ++q)
                    acc[r][cc] = fmaf(wv[cc + q], ka[p * 8 + q], acc[r][cc]);
        }
    }

    // ---- store: one float4 per row per thread; wave = 2 contiguous 512B runs ----
#pragma unroll
    for (int r = 0; r < 8; ++r) {
        const int orow = bi + tr + r;
        if (orow >= OH) continue;
        const int ocol = bj + tc;
        float* op = out + ((size_t)b * OH + orow) * OW + ocol;
        if (ocol + 3 < OW) {
            *(float4*)op = make_float4(acc[r][0], acc[r][1], acc[r][2], acc[r][3]);
        } else {
#pragma unroll
            for (int cc = 0; cc < 4; ++cc)
                if (ocol + cc < OW) op[cc] = acc[r][cc];
        }
    }
}

extern "C" void kernel_launch(void* const* d_in, const int* in_sizes, int n_in,
                              void* d_out, int out_size, void* d_ws, size_t ws_size,
                              hipStream_t stream) {
    const float* x = (const float*)d_in[0];
    const float* k = (const float*)d_in[1];
    float* out = (float*)d_out;

    dim3 grid((OW + TJ - 1) / TJ,   // 3
              (OH + TI - 1) / TI,   // 6
              BATCH);               // 128
    dim3 block(256);
    hipLaunchKernelGGL(corr_kernel, grid, block, 0, stream, x, k, out);
}

// Round 5
// 381.825 us; speedup vs baseline: 1.3499x; 1.3499x over previous
//
#include <hip/hip_runtime.h>

// Batched dynamic-filter cross-correlation:
// x: [128, 384, 384, 1] f32, k: [128, 8, 8, 1] f32
// out[b,i,j] = sum_{p,q} x[b,i+p,j+q] * k[b,p,q], out: [128, 377, 377, 1]
//
// R4 = R1 (known-clean traffic) with per-thread work doubled:
// each thread computes TWO 1x8 output strips (rows ty and ty+32).
// Everything else (staging idiom, k broadcast via LDS, store idiom,
// LDS stride 76 floats) kept identical to R1.
// (Resubmission: R4 bench was an infra failure, no data.)

#define BATCH 128
#define Hh 384
#define Ww 384
#define KH 8
#define KW 8
#define OH 377
#define OW 377

#define TI 64                 // output tile rows per block (R1: 32)
#define TJ 64                 // output tile cols per block
#define XR (TI + KH - 1)      // 71 input rows staged
#define XC4 18                // float4 columns loaded per row (72 floats >= 64+15)
#define XS4 19                // padded LDS row stride in float4 (76 floats)

__global__ __launch_bounds__(256, 2) void corr_kernel(
    const float* __restrict__ x,
    const float* __restrict__ k,
    float* __restrict__ out) {

    __shared__ float4 xs4[XR * XS4];   // 71*19*16 = 21,584 B
    __shared__ float  ks[KH * KW];

    const int tj = blockIdx.x;   // 0..5
    const int ti = blockIdx.y;   // 0..5
    const int b  = blockIdx.z;   // 0..127

    const int bi  = ti * TI;
    const int bj  = tj * TJ;
    const int tid = (int)threadIdx.x;

    // ---- stage k (64 floats) ----
    if (tid < 16) {
        ((float4*)ks)[tid] = ((const float4*)(k + (size_t)b * (KH * KW)))[tid];
    }

    // ---- stage x tile: rows bi..bi+70, cols bj..bj+71 (zero-fill OOB) ----
    const float* xb = x + (size_t)b * (Hh * Ww);
    for (int idx = tid; idx < XR * XC4; idx += 256) {
        const int r   = idx / XC4;
        const int c4  = idx - r * XC4;
        const int grow = bi + r;
        const int gcol = bj + c4 * 4;
        float4 v;
        if (grow < Hh && gcol + 3 < Ww) {
            v = *(const float4*)(xb + (size_t)grow * Ww + gcol);
        } else if (grow < Hh) {
            v.x = (gcol + 0 < Ww) ? xb[(size_t)grow * Ww + gcol + 0] : 0.f;
            v.y = (gcol + 1 < Ww) ? xb[(size_t)grow * Ww + gcol + 1] : 0.f;
            v.z = (gcol + 2 < Ww) ? xb[(size_t)grow * Ww + gcol + 2] : 0.f;
            v.w = (gcol + 3 < Ww) ? xb[(size_t)grow * Ww + gcol + 3] : 0.f;
        } else {
            v.x = v.y = v.z = v.w = 0.f;
        }
        xs4[r * XS4 + c4] = v;
    }
    __syncthreads();

    // ---- compute: each thread owns TWO 1x8 output strips (rows ty, ty+32) ----
    const int txg = tid & 7;     // j-group 0..7
    const int ty  = tid >> 3;    // 0..31
    const int j0  = txg * 8;     // local output col base (multiple of 8)

    float accA[8], accB[8];
#pragma unroll
    for (int jj = 0; jj < 8; ++jj) { accA[jj] = 0.f; accB[jj] = 0.f; }

    const float4* ks4 = (const float4*)ks;

#pragma unroll
    for (int p = 0; p < KH; ++p) {
        float4 k0 = ks4[p * 2 + 0];
        float4 k1 = ks4[p * 2 + 1];
        float kr[8] = {k0.x, k0.y, k0.z, k0.w, k1.x, k1.y, k1.z, k1.w};

        const float4* rowA = &xs4[(ty + p) * XS4 + (j0 >> 2)];
        float4 a0 = rowA[0], a1 = rowA[1], a2 = rowA[2], a3 = rowA[3];
        float wA[16] = {a0.x, a0.y, a0.z, a0.w, a1.x, a1.y, a1.z, a1.w,
                        a2.x, a2.y, a2.z, a2.w, a3.x, a3.y, a3.z, a3.w};

        const float4* rowB = &xs4[(ty + 32 + p) * XS4 + (j0 >> 2)];
        float4 b0 = rowB[0], b1 = rowB[1], b2 = rowB[2], b3 = rowB[3];
        float wB[16] = {b0.x, b0.y, b0.z, b0.w, b1.x, b1.y, b1.z, b1.w,
                        b2.x, b2.y, b2.z, b2.w, b3.x, b3.y, b3.z, b3.w};

#pragma unroll
        for (int q = 0; q < KW; ++q) {
#pragma unroll
            for (int jj = 0; jj < 8; ++jj) {
                accA[jj] = fmaf(wA[q + jj], kr[q], accA[jj]);
                accB[jj] = fmaf(wB[q + jj], kr[q], accB[jj]);
            }
        }
    }

    // ---- store (R1 idiom, twice) ----
    {
        const int oi = bi + ty;
        if (oi < OH) {
            float* ob = out + ((size_t)b * OH + oi) * OW;
#pragma unroll
            for (int jj = 0; jj < 8; ++jj) {
                const int oj = bj + j0 + jj;
                if (oj < OW) ob[oj] = accA[jj];
            }
        }
    }
    {
        const int oi = bi + ty + 32;
        if (oi < OH) {
            float* ob = out + ((size_t)b * OH + oi) * OW;
#pragma unroll
            for (int jj = 0; jj < 8; ++jj) {
                const int oj = bj + j0 + jj;
                if (oj < OW) ob[oj] = accB[jj];
            }
        }
    }
}

extern "C" void kernel_launch(void* const* d_in, const int* in_sizes, int n_in,
                              void* d_out, int out_size, void* d_ws, size_t ws_size,
                              hipStream_t stream) {
    const float* x = (const float*)d_in[0];
    const float* k = (const float*)d_in[1];
    float* out = (float*)d_out;

    dim3 grid((OW + TJ - 1) / TJ,   // 6
              (OH + TI - 1) / TI,   // 6
              BATCH);               // 128
    dim3 block(256);
    hipLaunchKernelGGL(corr_kernel, grid, block, 0, stream, x, k, out);
}